// Round 6
// baseline (380.109 us; speedup 1.0000x reference)
//
#include <hip/hip_runtime.h>
#include <stdint.h>

#define NN   2048
#define DD   128
#define DIN  256
#define ROWZ 75

typedef float f32x2 __attribute__((ext_vector_type(2)));
typedef float f32x4 __attribute__((ext_vector_type(4)));
typedef short bf16x8 __attribute__((ext_vector_type(8)));
typedef int   i32x4  __attribute__((ext_vector_type(4)));
typedef unsigned int u32x2 __attribute__((ext_vector_type(2)));

__device__ __forceinline__ unsigned short f2bf(float x){
  union { float f; unsigned int u; } v; v.f = x;
  unsigned int u = v.u;
  u += 0x7fffu + ((u >> 16) & 1u);   // RNE
  return (unsigned short)(u >> 16);
}

// ---------------------------------------------------------------------------
// Kernel A (R9): Wh = h @ W (fp32) + row L2 norms.
// 512 blocks x 512 threads (was 256): 2 blocks/CU x 8 waves = 4 waves/SIMD
// (R8 had 2/SIMD -> LDS->FMA latency exposed, ~12% FMA efficiency).
// Each thread: 2 rows x 4 d (acc[2][4]). Register-prefetched staging kept.
// batch = bid&7 keeps writer XCD == attn's reader XCD.
// ---------------------------------------------------------------------------
__launch_bounds__(512, 4)
__global__ void wh_kernel(const float* __restrict__ h, const float* __restrict__ W,
                          unsigned short* __restrict__ whn, unsigned short* __restrict__ whT)
{
  __shared__ float hs[32][36];     // [k][row]
  __shared__ float Ws[32][128];
  __shared__ float ssp[32][33];
  __shared__ float sinv[32];

  const int t   = threadIdx.x;
  const int bid = blockIdx.x;
  const int r0  = ((bid & 7) << 11) | ((bid >> 3) << 5);   // batch=bid&7
  const int r2  = (t >> 5) * 2;          // 2-row sub-base 0..30
  const int d4  = (t & 31) * 4;          // d sub-base 0..124

  float acc[2][4];
#pragma unroll
  for (int i = 0; i < 2; ++i)
#pragma unroll
    for (int j = 0; j < 4; ++j) acc[i][j] = 0.f;

  const int hrow = t >> 4;         // h stage: row 0..31
  const int hk   = (t & 15) * 2;   // h stage: k pair
  const int wk   = t >> 4;         // W stage: k row 0..31
  const int wd   = (t & 15) * 8;   // W stage: d base (8 floats/thread)

  // prefetch tile kt=0 into registers
  f32x2 ph = *(const f32x2*)(h + (size_t)(r0 + hrow) * DIN + hk);
  f32x4 pW0, pW1;
  {
    const float* ws = W + (size_t)wk * DD + wd;
    pW0 = ((const f32x4*)ws)[0];
    pW1 = ((const f32x4*)ws)[1];
  }

  for (int kt = 0; kt < 8; ++kt){
    __syncthreads();
    hs[hk][hrow]     = ph.x;
    hs[hk + 1][hrow] = ph.y;
    {
      f32x4* dst = (f32x4*)&Ws[wk][wd];
      dst[0] = pW0; dst[1] = pW1;
    }
    __syncthreads();

    if (kt < 7){                           // issue next tile's loads now
      ph = *(const f32x2*)(h + (size_t)(r0 + hrow) * DIN + (kt+1)*32 + hk);
      const float* ws = W + (size_t)((kt+1)*32 + wk) * DD + wd;
      pW0 = ((const f32x4*)ws)[0];
      pW1 = ((const f32x4*)ws)[1];
    }

#pragma unroll
    for (int k = 0; k < 32; ++k){
      f32x4 w4 = *(const f32x4*)&Ws[k][d4];
      f32x2 ha = *(const f32x2*)&hs[k][r2];
#pragma unroll
      for (int i = 0; i < 2; ++i)
#pragma unroll
        for (int j = 0; j < 4; ++j)
          acc[i][j] += ha[i] * w4[j];
    }
  }

  // row norms
#pragma unroll
  for (int i = 0; i < 2; ++i){
    float s = acc[i][0]*acc[i][0] + acc[i][1]*acc[i][1]
            + acc[i][2]*acc[i][2] + acc[i][3]*acc[i][3];
    ssp[r2 + i][t & 31] = s;
  }
  __syncthreads();
  if (t < 32){
    float ss = 0.f;
#pragma unroll
    for (int c = 0; c < 32; ++c) ss += ssp[t][c];
    sinv[t] = 1.0f / fmaxf(sqrtf(ss), 1e-12f);   // F.normalize eps semantics
  }
  __syncthreads();

  const int bb = r0 >> 11;
  const int n0 = (r0 & 2047) + r2;

  // whn: normalized bf16, row-major (2 rows/thread)
#pragma unroll
  for (int i = 0; i < 2; ++i){
    const float inv = sinv[r2 + i];
    unsigned int lo = (unsigned int)f2bf(acc[i][0]*inv) | ((unsigned int)f2bf(acc[i][1]*inv) << 16);
    unsigned int hi = (unsigned int)f2bf(acc[i][2]*inv) | ((unsigned int)f2bf(acc[i][3]*inv) << 16);
    u32x2 pk = { lo, hi };
    *(u32x2*)(whn + (size_t)(r0 + r2 + i) * DD + d4) = pk;
  }
  // whT: unnormalized bf16, transposed [b][d][n] (4B store per d; L2 merges
  // same-XCD neighbor blocks into full lines before HBM writeback)
#pragma unroll
  for (int j = 0; j < 4; ++j){
    unsigned int pk = (unsigned int)f2bf(acc[0][j]) | ((unsigned int)f2bf(acc[1][j]) << 16);
    *(unsigned int*)(whT + ((size_t)(bb * DD + d4 + j)) * NN + n0) = pk;
  }
}

// ---------------------------------------------------------------------------
// Kernel B (R9): 512 blocks x 512 threads, 32 q-rows/block, m-tile 256,
// 8 waves = 8 m-strips of 32, 8 iterations. 2 blocks/CU -> 4 waves/SIMD.
// Phase A: block's 512KB adj slab bit-packed into 8KB LDS with max-TLP
// coalesced dwordx4 streaming (lane ln owns u32 word ln of each row) ->
// ZERO global adj traffic in the main loop -> whn/whT stay L2-hot and
// kf/vf (direct global, R8-verified layouts) hit ~200cy L2, hidden by TLP.
// Main loop stays barrier-free (P wave-private, masks read-only).
// ---------------------------------------------------------------------------
__launch_bounds__(512, 4)
__global__ void attn_kernel(const unsigned short* __restrict__ whn,
                            const unsigned short* __restrict__ whT,
                            const int* __restrict__ adje,
                            float* __restrict__ out)
{
  __shared__ float smem[16384];     // 64 KB union:
                                    //  in-loop: Pbuf 8x[32x40]u16 @ [0,5120) + masks u32[32][65] @ [5120,7200)
                                    //  post:    fl [32][132] f32 @ [0,4224) ; epilogue: owf 64KB @ [0,16384)
  __shared__ float linv_s[32];

  const int t    = threadIdx.x;
  const int w    = t >> 6;
  const int l    = t & 63;
  const int quad = l >> 4;
  const int l16  = l & 15;
  const int ms   = w;                 // m-strip 0..7 (32 m-cols each)
  const int b     = blockIdx.x & 7;   // XCD-pinned batch (round-robin dispatch)
  const int qbase = (blockIdx.x >> 3) * 32;

  const unsigned short* whn_b = whn + (size_t)b * NN * DD;
  const unsigned short* whT_b = whT + (size_t)b * DD * NN;
  const int*            adj_b = adje + (size_t)b * NN * NN;

  unsigned short* const Pw = (unsigned short*)smem + w * (32 * 40);
  unsigned int*   const Mk = (unsigned int*)smem + 5120;    // [32][65]

  // ---- Phase A: bit-pack adj slab (32 rows x 2048) into LDS masks ----
  // wave w packs rows w*4..w*4+3; lane ln packs word ln (cols ln*32..+31)
  // 8 dwordx4 in flight/lane/row -> HBM-BW-limited burst.
  for (int rr = 0; rr < 4; ++rr){
    const int row = w*4 + rr;
    const int* src = adj_b + (size_t)(qbase + row) * NN + l*32;
    i32x4 c[8];
#pragma unroll
    for (int j = 0; j < 8; ++j) c[j] = *(const i32x4*)(src + j*4);
    unsigned int m = 0;
#pragma unroll
    for (int j = 0; j < 8; ++j)
#pragma unroll
      for (int e = 0; e < 4; ++e)
        m |= (unsigned int)(c[j][e] > 0) << (j*4 + e);
    Mk[row*65 + l] = m;
  }

  // Q fragments: rows qbase + s*16 + l16 (A-layout)
  bf16x8 qf[2][4];
#pragma unroll
  for (int s = 0; s < 2; ++s)
#pragma unroll
    for (int kc = 0; kc < 4; ++kc)
      qf[s][kc] = *(const bf16x8*)(whn_b + (size_t)(qbase + s*16 + l16) * DD + kc*32 + quad*8);

  f32x4 oacc[2][8];
  float lacc[2][4];
#pragma unroll
  for (int s = 0; s < 2; ++s){
#pragma unroll
    for (int dt = 0; dt < 8; ++dt) oacc[s][dt] = (f32x4){0.f, 0.f, 0.f, 0.f};
#pragma unroll
    for (int r = 0; r < 4; ++r) lacc[s][r] = 0.f;
  }

  // row-zeroing-bug predicate, hoisted
  bool zr[2][4];
#pragma unroll
  for (int s = 0; s < 2; ++s)
#pragma unroll
    for (int r = 0; r < 4; ++r)
      zr[s][r] = (qbase + s*16 + quad*4 + r) < ROWZ;

  __syncthreads();   // masks visible to all waves

  for (int it = 0; it < 8; ++it){
    const int m0 = it * 256;

    // ---- K fragments direct from global (L2-hot now): rows m0+ms*32+2*l16+f ----
    bf16x8 kf[2][4];
#pragma unroll
    for (int f = 0; f < 2; ++f)
#pragma unroll
      for (int kc = 0; kc < 4; ++kc)
        kf[f][kc] = *(const bf16x8*)(whn_b + (size_t)(m0 + ms*32 + 2*l16 + f) * DD + kc*32 + quad*8);

    // ---- mask words from LDS (broadcast; 16 lanes/quad share an address) ----
    unsigned int aw[2][4];
#pragma unroll
    for (int s = 0; s < 2; ++s)
#pragma unroll
      for (int r = 0; r < 4; ++r)
        aw[s][r] = Mk[(s*16 + quad*4 + r)*65 + it*8 + ms];

    // ---- QK + mask + exp -> packed P (u32 = 2 adjacent m-cols) ----
#pragma unroll
    for (int s = 0; s < 2; ++s){
      f32x4 sc0 = (f32x4){0.f,0.f,0.f,0.f};
      f32x4 sc1 = (f32x4){0.f,0.f,0.f,0.f};
#pragma unroll
      for (int kc = 0; kc < 4; ++kc){
        sc0 = __builtin_amdgcn_mfma_f32_16x16x32_bf16(qf[s][kc], kf[0][kc], sc0, 0, 0, 0);
        sc1 = __builtin_amdgcn_mfma_f32_16x16x32_bf16(qf[s][kc], kf[1][kc], sc1, 0, 0, 0);
      }
#pragma unroll
      for (int r = 0; r < 4; ++r){
        float sv0 = zr[s][r] ? 0.f : sc0[r];
        float sv1 = zr[s][r] ? 0.f : sc1[r];
        float p0 = ((aw[s][r] >> (2*l16    )) & 1u) ? __expf(sv0) : 0.f;
        float p1 = ((aw[s][r] >> (2*l16 + 1)) & 1u) ? __expf(sv1) : 0.f;
        lacc[s][r] += p0 + p1;
        unsigned int pk = (unsigned int)f2bf(p0) | ((unsigned int)f2bf(p1) << 16);
        *(unsigned int*)&Pw[(s*16 + quad*4 + r) * 40 + 2*l16] = pk;
      }
    }

    // ---- PV: P A-frags from own LDS; V B-frags direct from global (L2) ----
    bf16x8 pfr0 = *(const bf16x8*)&Pw[(l16) * 40 + quad*8];
    bf16x8 pfr1 = *(const bf16x8*)&Pw[(16 + l16) * 40 + quad*8];
    bf16x8 vf[8];
#pragma unroll
    for (int dt = 0; dt < 8; ++dt)
      vf[dt] = *(const bf16x8*)(whT_b + (size_t)(dt*16 + l16) * NN + m0 + ms*32 + quad*8);
    __builtin_amdgcn_s_setprio(1);
#pragma unroll
    for (int dt = 0; dt < 8; ++dt){
      oacc[0][dt] = __builtin_amdgcn_mfma_f32_16x16x32_bf16(pfr0, vf[dt], oacc[0][dt], 0, 0, 0);
      oacc[1][dt] = __builtin_amdgcn_mfma_f32_16x16x32_bf16(pfr1, vf[dt], oacc[1][dt], 0, 0, 0);
    }
    __builtin_amdgcn_s_setprio(0);
  }

  __syncthreads();   // all waves done with Pw/masks before fl overlays

  // ---- l reduction: fl[qrow32][w*16+l16] (sum over 8 strips x 16 lanes) ----
  {
    float* fl = smem;   // [32][132]
#pragma unroll
    for (int s = 0; s < 2; ++s)
#pragma unroll
      for (int r = 0; r < 4; ++r)
        fl[(s*16 + quad*4 + r) * 132 + w*16 + l16] = lacc[s][r];
  }
  __syncthreads();
  if (t < 32){
    const float* fl = smem;
    float sum = 0.f;
#pragma unroll
    for (int c = 0; c < 128; ++c) sum += fl[t * 132 + c];
    linv_s[t] = 1.0f / sum;
  }

  // ---- output: reduce oacc across 8 m-strips (owf = full 64KB smem) ----
  float* const owf = smem;    // [wave][16 rows][128 d]
  for (int s = 0; s < 2; ++s){
    __syncthreads();   // linv visible (s=0) / previous pass reads done
#pragma unroll
    for (int dt = 0; dt < 8; ++dt)
#pragma unroll
      for (int r = 0; r < 4; ++r)
        owf[w*2048 + (quad*4 + r)*128 + dt*16 + l16] = oacc[s][dt][r];
    __syncthreads();
#pragma unroll
    for (int j = 0; j < 4; ++j){
      const int o   = j*512 + t;          // 2048 = 16 rows x 128 d
      const int r16 = o >> 7;
      const int d   = o & 127;
      float v = 0.f;
#pragma unroll
      for (int ww = 0; ww < 8; ++ww)
        v += owf[ww*2048 + r16*128 + d];
      const int qrl = s*16 + r16;
      v *= linv_s[qrl];
      v = (v > 0.f) ? v : expm1f(v);      // ELU (alpha=1)
      out[(size_t)(b*NN + qbase + qrl) * DD + d] = v;
    }
  }
}

extern "C" void kernel_launch(void* const* d_in, const int* in_sizes, int n_in,
                              void* d_out, int out_size, void* d_ws, size_t ws_size,
                              hipStream_t stream)
{
  const float* h       = (const float*)d_in[0];
  // d_in[1] = adj  (unused by the reference)
  const int*   adj_eye = (const int*)d_in[2];
  const float* W       = (const float*)d_in[3];
  float*       out     = (float*)d_out;

  unsigned short* whn  = (unsigned short*)d_ws;                   // 16384*128 bf16 = 4 MB
  unsigned short* whT  = whn + (size_t)16384 * 128;               // 8*128*2048 bf16 = 4 MB

  wh_kernel<<<512, 512, 0, stream>>>(h, W, whn, whT);
  attn_kernel<<<512, 512, 0, stream>>>(whn, whT, adj_eye, out);
}

// Round 7
// 331.527 us; speedup vs baseline: 1.1465x; 1.1465x over previous
//
#include <hip/hip_runtime.h>
#include <stdint.h>

#define NN   2048
#define DD   128
#define DIN  256
#define ROWZ 75

typedef float f32x2 __attribute__((ext_vector_type(2)));
typedef float f32x4 __attribute__((ext_vector_type(4)));
typedef short bf16x8 __attribute__((ext_vector_type(8)));
typedef int   i32x4  __attribute__((ext_vector_type(4)));
typedef unsigned int u32x2 __attribute__((ext_vector_type(2)));

__device__ __forceinline__ unsigned short f2bf(float x){
  union { float f; unsigned int u; } v; v.f = x;
  unsigned int u = v.u;
  u += 0x7fffu + ((u >> 16) & 1u);   // RNE
  return (unsigned short)(u >> 16);
}
__device__ __forceinline__ float bf2f(unsigned short b){
  union { float f; unsigned int u; } v; v.u = ((unsigned int)b) << 16;
  return v.f;
}

// ---------------------------------------------------------------------------
// Kernel A (R10): Wh = h @ W via MFMA with bf16x3 split (~fp32 accuracy).
// R5-R9's fp32-FMA version was LDS-throughput-bound (24B LDS per 16 FLOP ->
// ~60us/CU floor). MFMA cuts LDS bytes/FLOP 8x and uses the idle matrix pipe.
//   h = ahi + alo (bf16 pair, split in-register from fp32 global loads)
//   W = bhi + blo (bf16 pair, staged TRANSPOSED in LDS per 32-k tile)
//   Wh ~= ahi*bhi + ahi*blo + alo*bhi   (dropped alo*blo ~ 2^-18 relative)
// whT (= Wh^T) computed FREE by re-issuing each MFMA with swapped operands
// (same register fragments -> C^T), making whT stores coalesced.
// 256 blocks x 512 thr: 64 rows x 128 cols/block; 8 waves = 4 row-quads x
// 2 col-halves; per wave 16x64 out, 24 MFMA per 32-k step.
// ---------------------------------------------------------------------------
__launch_bounds__(512, 2)
__global__ void wh_kernel(const float* __restrict__ h, const float* __restrict__ W,
                          unsigned short* __restrict__ whn, unsigned short* __restrict__ whT)
{
  __shared__ unsigned short WhiT[128][40];   // [d][k] hi, pad 40: conflict-free b128
  __shared__ unsigned short WloT[128][40];   // [d][k] lo
  __shared__ float ssp[64][3];
  __shared__ float sinv_s[64];

  const int t    = threadIdx.x;
  const int bid  = blockIdx.x;
  const int r0   = ((bid & 7) << 11) | ((bid >> 3) << 6);  // batch=bid&7 (XCD pin)
  const int w    = t >> 6;
  const int l    = t & 63;
  const int quad = l >> 4;
  const int l16  = l & 15;
  const int wr   = (w & 3) * 16;    // wave row base 0..48
  const int nc   = (w >> 2) * 64;   // wave col half 0/64
  const int ch   = w >> 2;

  // W staging: thread -> (d = t&127, k-octet = (t>>7)*8)
  const int sd = t & 127;
  const int sk = (t >> 7) * 8;

  f32x4 acc[4], occ[4];
#pragma unroll
  for (int ns = 0; ns < 4; ++ns){
    acc[ns] = (f32x4){0.f,0.f,0.f,0.f};
    occ[ns] = (f32x4){0.f,0.f,0.f,0.f};
  }

  // prefetch tile kt=0: W octet (8 strided dwords) + h frag (2x f32x4)
  float wv[8];
#pragma unroll
  for (int j = 0; j < 8; ++j) wv[j] = W[(size_t)(sk + j) * DD + sd];
  const float* hrow = h + (size_t)(r0 + wr + l16) * DIN;
  f32x4 hv0 = *(const f32x4*)(hrow + quad*8);
  f32x4 hv1 = *(const f32x4*)(hrow + quad*8 + 4);

  for (int kt = 0; kt < 8; ++kt){
    __syncthreads();                 // prior tile's readers done
    { // split W octet -> hi/lo bf16, write transposed (conflict-free pattern)
      bf16x8 whi8, wlo8;
#pragma unroll
      for (int j = 0; j < 8; ++j){
        float x = wv[j];
        unsigned short hb = f2bf(x);
        whi8[j] = (short)hb;
        wlo8[j] = (short)f2bf(x - bf2f(hb));
      }
      *(bf16x8*)&WhiT[sd][sk] = whi8;
      *(bf16x8*)&WloT[sd][sk] = wlo8;
    }
    // split h frag -> ahi/alo (k = quad*8 + j)
    bf16x8 ahi, alo;
#pragma unroll
    for (int e = 0; e < 4; ++e){
      unsigned short hb0 = f2bf(hv0[e]), hb1 = f2bf(hv1[e]);
      ahi[e]   = (short)hb0;  alo[e]   = (short)f2bf(hv0[e] - bf2f(hb0));
      ahi[4+e] = (short)hb1;  alo[4+e] = (short)f2bf(hv1[e] - bf2f(hb1));
    }
    __syncthreads();                 // tile visible

    if (kt < 7){                     // issue next tile's loads (land during MFMAs)
      const int k0n = (kt + 1) * 32;
#pragma unroll
      for (int j = 0; j < 8; ++j) wv[j] = W[(size_t)(k0n + sk + j) * DD + sd];
      hv0 = *(const f32x4*)(hrow + k0n + quad*8);
      hv1 = *(const f32x4*)(hrow + k0n + quad*8 + 4);
    }

#pragma unroll
    for (int ns = 0; ns < 4; ++ns){
      bf16x8 bhi = *(const bf16x8*)&WhiT[nc + ns*16 + l16][quad*8];
      bf16x8 blo = *(const bf16x8*)&WloT[nc + ns*16 + l16][quad*8];
      // forward: C[h-row][d]
      acc[ns] = __builtin_amdgcn_mfma_f32_16x16x32_bf16(ahi, bhi, acc[ns], 0, 0, 0);
      acc[ns] = __builtin_amdgcn_mfma_f32_16x16x32_bf16(alo, bhi, acc[ns], 0, 0, 0);
      acc[ns] = __builtin_amdgcn_mfma_f32_16x16x32_bf16(ahi, blo, acc[ns], 0, 0, 0);
      // transposed: C^T[d][h-row] — same fragments, swapped operands
      occ[ns] = __builtin_amdgcn_mfma_f32_16x16x32_bf16(bhi, ahi, occ[ns], 0, 0, 0);
      occ[ns] = __builtin_amdgcn_mfma_f32_16x16x32_bf16(bhi, alo, occ[ns], 0, 0, 0);
      occ[ns] = __builtin_amdgcn_mfma_f32_16x16x32_bf16(blo, ahi, occ[ns], 0, 0, 0);
    }
  }

  // ---- row L2 norms: reduce acc^2 over ns, then over the 16 lanes of l16 ----
#pragma unroll
  for (int r = 0; r < 4; ++r){
    float val = 0.f;
#pragma unroll
    for (int ns = 0; ns < 4; ++ns) val += acc[ns][r] * acc[ns][r];
    val += __shfl_xor(val, 1);
    val += __shfl_xor(val, 2);
    val += __shfl_xor(val, 4);
    val += __shfl_xor(val, 8);
    if (l16 == 0) ssp[wr + quad*4 + r][ch] = val;
  }
  __syncthreads();
  if (t < 64){
    float ss = ssp[t][0] + ssp[t][1];
    sinv_s[t] = 1.0f / fmaxf(sqrtf(ss), 1e-12f);   // F.normalize eps semantics
  }
  __syncthreads();

  const int bb = r0 >> 11;
  const int n0 = (r0 & 2047) + wr;

  // whn: normalized bf16 [n][d] — C frags; 16-lane groups hit 32B segments
#pragma unroll
  for (int ns = 0; ns < 4; ++ns)
#pragma unroll
    for (int r = 0; r < 4; ++r){
      const int row = wr + quad*4 + r;
      whn[(size_t)(r0 + row) * DD + nc + ns*16 + l16] = f2bf(acc[ns][r] * sinv_s[row]);
    }
  // whT: unnormalized bf16 [b][d][n] — C^T frags; coalesced over l16 (= n)
#pragma unroll
  for (int ns = 0; ns < 4; ++ns)
#pragma unroll
    for (int r = 0; r < 4; ++r){
      const int d = nc + ns*16 + quad*4 + r;
      whT[((size_t)(bb * DD + d)) * NN + n0 + l16] = f2bf(occ[ns][r]);
    }
}

// ---------------------------------------------------------------------------
// Kernel B (R10 = R9 body, launch_bounds fixed): R9's __launch_bounds__(512,4)
// capped VGPR at 64 -> live set ~160 spilled to scratch (WRITE_SIZE 87MB,
// FETCH +100MB). (512,2) = R8's proven setting (112 VGPR, zero spill);
// grid 512 gives 2 blocks/CU -> 4 waves/SIMD.
// ---------------------------------------------------------------------------
__launch_bounds__(512, 2)
__global__ void attn_kernel(const unsigned short* __restrict__ whn,
                            const unsigned short* __restrict__ whT,
                            const int* __restrict__ adje,
                            float* __restrict__ out)
{
  __shared__ float smem[16384];     // 64 KB union (Pbuf+masks / fl / owf)
  __shared__ float linv_s[32];

  const int t    = threadIdx.x;
  const int w    = t >> 6;
  const int l    = t & 63;
  const int quad = l >> 4;
  const int l16  = l & 15;
  const int ms   = w;                 // m-strip 0..7
  const int b     = blockIdx.x & 7;   // XCD-pinned batch
  const int qbase = (blockIdx.x >> 3) * 32;

  const unsigned short* whn_b = whn + (size_t)b * NN * DD;
  const unsigned short* whT_b = whT + (size_t)b * DD * NN;
  const int*            adj_b = adje + (size_t)b * NN * NN;

  unsigned short* const Pw = (unsigned short*)smem + w * (32 * 40);
  unsigned int*   const Mk = (unsigned int*)smem + 5120;    // [32][65]

  // ---- Phase A: bit-pack the block's 32x2048 adj slab into 8KB LDS ----
#pragma unroll 1
  for (int rr = 0; rr < 4; ++rr){
    const int row = w*4 + rr;
    const int* src = adj_b + (size_t)(qbase + row) * NN + l*32;
    i32x4 c[8];
#pragma unroll
    for (int j = 0; j < 8; ++j) c[j] = *(const i32x4*)(src + j*4);
    unsigned int m = 0;
#pragma unroll
    for (int j = 0; j < 8; ++j)
#pragma unroll
      for (int e = 0; e < 4; ++e)
        m |= (unsigned int)(c[j][e] > 0) << (j*4 + e);
    Mk[row*65 + l] = m;
  }

  // Q fragments (A-layout)
  bf16x8 qf[2][4];
#pragma unroll
  for (int s = 0; s < 2; ++s)
#pragma unroll
    for (int kc = 0; kc < 4; ++kc)
      qf[s][kc] = *(const bf16x8*)(whn_b + (size_t)(qbase + s*16 + l16) * DD + kc*32 + quad*8);

  f32x4 oacc[2][8];
  float lacc[2][4];
#pragma unroll
  for (int s = 0; s < 2; ++s){
#pragma unroll
    for (int dt = 0; dt < 8; ++dt) oacc[s][dt] = (f32x4){0.f, 0.f, 0.f, 0.f};
#pragma unroll
    for (int r = 0; r < 4; ++r) lacc[s][r] = 0.f;
  }

  bool zr[2][4];
#pragma unroll
  for (int s = 0; s < 2; ++s)
#pragma unroll
    for (int r = 0; r < 4; ++r)
      zr[s][r] = (qbase + s*16 + quad*4 + r) < ROWZ;

  __syncthreads();   // masks visible

  for (int it = 0; it < 8; ++it){
    const int m0 = it * 256;

    bf16x8 kf[2][4];
#pragma unroll
    for (int f = 0; f < 2; ++f)
#pragma unroll
      for (int kc = 0; kc < 4; ++kc)
        kf[f][kc] = *(const bf16x8*)(whn_b + (size_t)(m0 + ms*32 + 2*l16 + f) * DD + kc*32 + quad*8);

    unsigned int aw[2][4];
#pragma unroll
    for (int s = 0; s < 2; ++s)
#pragma unroll
      for (int r = 0; r < 4; ++r)
        aw[s][r] = Mk[(s*16 + quad*4 + r)*65 + it*8 + ms];

#pragma unroll
    for (int s = 0; s < 2; ++s){
      f32x4 sc0 = (f32x4){0.f,0.f,0.f,0.f};
      f32x4 sc1 = (f32x4){0.f,0.f,0.f,0.f};
#pragma unroll
      for (int kc = 0; kc < 4; ++kc){
        sc0 = __builtin_amdgcn_mfma_f32_16x16x32_bf16(qf[s][kc], kf[0][kc], sc0, 0, 0, 0);
        sc1 = __builtin_amdgcn_mfma_f32_16x16x32_bf16(qf[s][kc], kf[1][kc], sc1, 0, 0, 0);
      }
#pragma unroll
      for (int r = 0; r < 4; ++r){
        float sv0 = zr[s][r] ? 0.f : sc0[r];
        float sv1 = zr[s][r] ? 0.f : sc1[r];
        float p0 = ((aw[s][r] >> (2*l16    )) & 1u) ? __expf(sv0) : 0.f;
        float p1 = ((aw[s][r] >> (2*l16 + 1)) & 1u) ? __expf(sv1) : 0.f;
        lacc[s][r] += p0 + p1;
        unsigned int pk = (unsigned int)f2bf(p0) | ((unsigned int)f2bf(p1) << 16);
        *(unsigned int*)&Pw[(s*16 + quad*4 + r) * 40 + 2*l16] = pk;
      }
    }

    bf16x8 pfr0 = *(const bf16x8*)&Pw[(l16) * 40 + quad*8];
    bf16x8 pfr1 = *(const bf16x8*)&Pw[(16 + l16) * 40 + quad*8];
    bf16x8 vf[8];
#pragma unroll
    for (int dt = 0; dt < 8; ++dt)
      vf[dt] = *(const bf16x8*)(whT_b + (size_t)(dt*16 + l16) * NN + m0 + ms*32 + quad*8);
    __builtin_amdgcn_s_setprio(1);
#pragma unroll
    for (int dt = 0; dt < 8; ++dt){
      oacc[0][dt] = __builtin_amdgcn_mfma_f32_16x16x32_bf16(pfr0, vf[dt], oacc[0][dt], 0, 0, 0);
      oacc[1][dt] = __builtin_amdgcn_mfma_f32_16x16x32_bf16(pfr1, vf[dt], oacc[1][dt], 0, 0, 0);
    }
    __builtin_amdgcn_s_setprio(0);
  }

  __syncthreads();   // Pw/masks reads done before fl overlays

  {
    float* fl = smem;   // [32][132]
#pragma unroll
    for (int s = 0; s < 2; ++s)
#pragma unroll
      for (int r = 0; r < 4; ++r)
        fl[(s*16 + quad*4 + r) * 132 + w*16 + l16] = lacc[s][r];
  }
  __syncthreads();
  if (t < 32){
    const float* fl = smem;
    float sum = 0.f;
#pragma unroll
    for (int c = 0; c < 128; ++c) sum += fl[t * 132 + c];
    linv_s[t] = 1.0f / sum;
  }

  float* const owf = smem;    // [wave][16 rows][128 d]
  for (int s = 0; s < 2; ++s){
    __syncthreads();
#pragma unroll
    for (int dt = 0; dt < 8; ++dt)
#pragma unroll
      for (int r = 0; r < 4; ++r)
        owf[w*2048 + (quad*4 + r)*128 + dt*16 + l16] = oacc[s][dt][r];
    __syncthreads();
#pragma unroll
    for (int j = 0; j < 4; ++j){
      const int o   = j*512 + t;
      const int r16 = o >> 7;
      const int d   = o & 127;
      float v = 0.f;
#pragma unroll
      for (int ww = 0; ww < 8; ++ww)
        v += owf[ww*2048 + r16*128 + d];
      const int qrl = s*16 + r16;
      v *= linv_s[qrl];
      v = (v > 0.f) ? v : expm1f(v);      // ELU (alpha=1)
      out[(size_t)(b*NN + qbase + qrl) * DD + d] = v;
    }
  }
}

extern "C" void kernel_launch(void* const* d_in, const int* in_sizes, int n_in,
                              void* d_out, int out_size, void* d_ws, size_t ws_size,
                              hipStream_t stream)
{
  const float* h       = (const float*)d_in[0];
  // d_in[1] = adj  (unused by the reference)
  const int*   adj_eye = (const int*)d_in[2];
  const float* W       = (const float*)d_in[3];
  float*       out     = (float*)d_out;

  unsigned short* whn  = (unsigned short*)d_ws;                   // 16384*128 bf16 = 4 MB
  unsigned short* whT  = whn + (size_t)16384 * 128;               // 8*128*2048 bf16 = 4 MB

  wh_kernel<<<256, 512, 0, stream>>>(h, W, whn, whT);
  attn_kernel<<<512, 512, 0, stream>>>(whn, whT, adj_eye, out);
}

// Round 8
// 282.688 us; speedup vs baseline: 1.3446x; 1.1728x over previous
//
#include <hip/hip_runtime.h>
#include <stdint.h>

#define NN   2048
#define DD   128
#define DIN  256
#define ROWZ 75

typedef float f32x4 __attribute__((ext_vector_type(4)));
typedef short bf16x8 __attribute__((ext_vector_type(8)));
typedef unsigned int u32x2 __attribute__((ext_vector_type(2)));

__device__ __forceinline__ unsigned short f2bf(float x){
  union { float f; unsigned int u; } v; v.f = x;
  unsigned int u = v.u;
  u += 0x7fffu + ((u >> 16) & 1u);   // RNE
  return (unsigned short)(u >> 16);
}
__device__ __forceinline__ float bf2f(unsigned short b){
  union { float f; unsigned int u; } v; v.u = ((unsigned int)b) << 16;
  return v.f;
}

// ---------------------------------------------------------------------------
// Kernel A (= R10 wh, best measured ~35us): Wh = h @ W via MFMA, bf16x3 split.
//   h = ahi+alo, W = bhi+blo (staged transposed in LDS); Wh ~= ahi*bhi +
//   ahi*blo + alo*bhi (dropped alo*blo ~2^-18, dominated by bf16 output rnd).
// whT computed FREE by re-issuing MFMAs with swapped operands -> C^T frags,
// coalesced whT stores. 256 blocks x 512 thr, 64 rows x 128 cols per block.
// ---------------------------------------------------------------------------
__launch_bounds__(512, 2)
__global__ void wh_kernel(const float* __restrict__ h, const float* __restrict__ W,
                          unsigned short* __restrict__ whn, unsigned short* __restrict__ whT)
{
  __shared__ unsigned short WhiT[128][40];   // [d][k] hi, pad 40: conflict-free b128
  __shared__ unsigned short WloT[128][40];   // [d][k] lo
  __shared__ float ssp[64][3];
  __shared__ float sinv_s[64];

  const int t    = threadIdx.x;
  const int bid  = blockIdx.x;
  const int r0   = ((bid & 7) << 11) | ((bid >> 3) << 6);  // batch=bid&7 (XCD pin)
  const int w    = t >> 6;
  const int l    = t & 63;
  const int quad = l >> 4;
  const int l16  = l & 15;
  const int wr   = (w & 3) * 16;    // wave row base 0..48
  const int nc   = (w >> 2) * 64;   // wave col half 0/64
  const int ch   = w >> 2;

  const int sd = t & 127;           // W staging: d
  const int sk = (t >> 7) * 8;      // W staging: k-octet

  f32x4 acc[4], occ[4];
#pragma unroll
  for (int ns = 0; ns < 4; ++ns){
    acc[ns] = (f32x4){0.f,0.f,0.f,0.f};
    occ[ns] = (f32x4){0.f,0.f,0.f,0.f};
  }

  // prefetch tile kt=0
  float wv[8];
#pragma unroll
  for (int j = 0; j < 8; ++j) wv[j] = W[(size_t)(sk + j) * DD + sd];
  const float* hrow = h + (size_t)(r0 + wr + l16) * DIN;
  f32x4 hv0 = *(const f32x4*)(hrow + quad*8);
  f32x4 hv1 = *(const f32x4*)(hrow + quad*8 + 4);

  for (int kt = 0; kt < 8; ++kt){
    __syncthreads();
    { // split W octet -> hi/lo bf16, write transposed
      bf16x8 whi8, wlo8;
#pragma unroll
      for (int j = 0; j < 8; ++j){
        float x = wv[j];
        unsigned short hb = f2bf(x);
        whi8[j] = (short)hb;
        wlo8[j] = (short)f2bf(x - bf2f(hb));
      }
      *(bf16x8*)&WhiT[sd][sk] = whi8;
      *(bf16x8*)&WloT[sd][sk] = wlo8;
    }
    bf16x8 ahi, alo;
#pragma unroll
    for (int e = 0; e < 4; ++e){
      unsigned short hb0 = f2bf(hv0[e]), hb1 = f2bf(hv1[e]);
      ahi[e]   = (short)hb0;  alo[e]   = (short)f2bf(hv0[e] - bf2f(hb0));
      ahi[4+e] = (short)hb1;  alo[4+e] = (short)f2bf(hv1[e] - bf2f(hb1));
    }
    __syncthreads();

    if (kt < 7){
      const int k0n = (kt + 1) * 32;
#pragma unroll
      for (int j = 0; j < 8; ++j) wv[j] = W[(size_t)(k0n + sk + j) * DD + sd];
      hv0 = *(const f32x4*)(hrow + k0n + quad*8);
      hv1 = *(const f32x4*)(hrow + k0n + quad*8 + 4);
    }

#pragma unroll
    for (int ns = 0; ns < 4; ++ns){
      bf16x8 bhi = *(const bf16x8*)&WhiT[nc + ns*16 + l16][quad*8];
      bf16x8 blo = *(const bf16x8*)&WloT[nc + ns*16 + l16][quad*8];
      acc[ns] = __builtin_amdgcn_mfma_f32_16x16x32_bf16(ahi, bhi, acc[ns], 0, 0, 0);
      acc[ns] = __builtin_amdgcn_mfma_f32_16x16x32_bf16(alo, bhi, acc[ns], 0, 0, 0);
      acc[ns] = __builtin_amdgcn_mfma_f32_16x16x32_bf16(ahi, blo, acc[ns], 0, 0, 0);
      occ[ns] = __builtin_amdgcn_mfma_f32_16x16x32_bf16(bhi, ahi, occ[ns], 0, 0, 0);
      occ[ns] = __builtin_amdgcn_mfma_f32_16x16x32_bf16(bhi, alo, occ[ns], 0, 0, 0);
      occ[ns] = __builtin_amdgcn_mfma_f32_16x16x32_bf16(blo, ahi, occ[ns], 0, 0, 0);
    }
  }

  // row L2 norms
#pragma unroll
  for (int r = 0; r < 4; ++r){
    float val = 0.f;
#pragma unroll
    for (int ns = 0; ns < 4; ++ns) val += acc[ns][r] * acc[ns][r];
    val += __shfl_xor(val, 1);
    val += __shfl_xor(val, 2);
    val += __shfl_xor(val, 4);
    val += __shfl_xor(val, 8);
    if (l16 == 0) ssp[wr + quad*4 + r][ch] = val;
  }
  __syncthreads();
  if (t < 64){
    float ss = ssp[t][0] + ssp[t][1];
    sinv_s[t] = 1.0f / fmaxf(sqrtf(ss), 1e-12f);   // F.normalize eps semantics
  }
  __syncthreads();

  const int bb = r0 >> 11;
  const int n0 = (r0 & 2047) + wr;

#pragma unroll
  for (int ns = 0; ns < 4; ++ns)
#pragma unroll
    for (int r = 0; r < 4; ++r){
      const int row = wr + quad*4 + r;
      whn[(size_t)(r0 + row) * DD + nc + ns*16 + l16] = f2bf(acc[ns][r] * sinv_s[row]);
    }
#pragma unroll
  for (int ns = 0; ns < 4; ++ns)
#pragma unroll
    for (int r = 0; r < 4; ++r){
      const int d = nc + ns*16 + quad*4 + r;
      whT[((size_t)(bb * DD + d)) * NN + n0 + l16] = f2bf(occ[ns][r]);
    }
}

// ---------------------------------------------------------------------------
// Kernel B (= R7 attn, best measured ~58us): 256 blocks x 512 threads,
// 64 q-rows/block. K AND V tiles DMA-staged (global_load_lds, pre-swizzled
// src), double-buffered; adj direct from global with 1-iter register
// prefetch; ONE barrier/iter (end-of-iter vmcnt(0) is ~free: DMA had the
// whole iteration in flight). R8/R10's direct-global K/V put vmem latency
// on the per-iter critical path and regressed 1.7-2x — staging stays.
// ---------------------------------------------------------------------------
__launch_bounds__(512, 2)
__global__ void attn_kernel(const unsigned short* __restrict__ whn,
                            const unsigned short* __restrict__ whT,
                            const int* __restrict__ adje,
                            float* __restrict__ out)
{
  __shared__ unsigned short Kt[2][128 * 128];   // 64 KB K-tile (rows = m, cols = d)
  __shared__ unsigned short Vt[2][128 * 128];   // 64 KB V-tile (rows = d, cols = n)
  __shared__ unsigned short Pbuf[8][32 * 40];   // 20 KB per-wave P
  __shared__ float linv_s[64];

  const int t    = threadIdx.x;
  const int w    = t >> 6;
  const int l    = t & 63;
  const int quad = l >> 4;
  const int l16  = l & 15;
  const int qh   = w >> 2;            // q-half 0/1
  const int ms   = w & 3;             // m-strip 0..3
  const int b     = blockIdx.x & 7;   // XCD-pinned batch (round-robin dispatch)
  const int qbase = (blockIdx.x >> 3) * 64;

  const unsigned short* whn_b = whn + (size_t)b * NN * DD;
  const unsigned short* whT_b = whT + (size_t)b * DD * NN;
  const int*            adj_b = adje + (size_t)b * NN * NN;

#define STAGE(M0, CC)                                                          \
  if (w < 4){                                                                  \
    _Pragma("unroll")                                                          \
    for (int ii = 0; ii < 8; ++ii){                                            \
      const int row = w*32 + ii*4 + (l >> 4);                                  \
      const unsigned short* src = whn_b + (size_t)((M0) + row) * DD            \
                                  + (l16 ^ (row & 7)) * 8;                     \
      __builtin_amdgcn_global_load_lds(                                        \
          (const __attribute__((address_space(1))) void*)src,                  \
          (__attribute__((address_space(3))) void*)&Kt[CC][(w*32 + ii*4)*128], \
          16, 0, 0);                                                           \
    }                                                                          \
  } else {                                                                     \
    _Pragma("unroll")                                                          \
    for (int ii = 0; ii < 8; ++ii){                                            \
      const int dv = (w-4)*32 + ii*4 + (l >> 4);                               \
      const unsigned short* src = whT_b + (size_t)dv * NN + (M0)               \
                                  + (l16 ^ (dv & 7)) * 8;                      \
      __builtin_amdgcn_global_load_lds(                                        \
          (const __attribute__((address_space(1))) void*)src,                  \
          (__attribute__((address_space(3))) void*)&Vt[CC][((w-4)*32+ii*4)*128],\
          16, 0, 0);                                                           \
    }                                                                          \
  }

  // Q fragments
  bf16x8 qf[2][4];
#pragma unroll
  for (int s = 0; s < 2; ++s)
#pragma unroll
    for (int kc = 0; kc < 4; ++kc)
      qf[s][kc] = *(const bf16x8*)(whn_b + (size_t)(qbase + qh*32 + s*16 + l16) * DD + kc*32 + quad*8);

  f32x4 oacc[2][8];
  float lacc[2][4];
#pragma unroll
  for (int s = 0; s < 2; ++s){
#pragma unroll
    for (int dt = 0; dt < 8; ++dt) oacc[s][dt] = (f32x4){0.f, 0.f, 0.f, 0.f};
#pragma unroll
    for (int r = 0; r < 4; ++r) lacc[s][r] = 0.f;
  }

  unsigned short* const Pw = &Pbuf[w][0];

  // prologue: adj(0) + tiles(0)
  int av[2][2][4];
#pragma unroll
  for (int f = 0; f < 2; ++f)
#pragma unroll
    for (int s = 0; s < 2; ++s)
#pragma unroll
      for (int r = 0; r < 4; ++r)
        av[f][s][r] = adj_b[(size_t)(qbase + qh*32 + s*16 + quad*4 + r) * NN + ms*32 + f*16 + l16];
  STAGE(0, 0)
  __syncthreads();

  for (int it = 0; it < 16; ++it){
    const int m0  = it * 128;
    const int cur = it & 1;

    // prefetch it+1: adj -> regs, K/V tiles -> other LDS buffer
    int avn[2][2][4];
    if (it < 15){
      const int mn = m0 + 128;
#pragma unroll
      for (int f = 0; f < 2; ++f)
#pragma unroll
        for (int s = 0; s < 2; ++s)
#pragma unroll
          for (int r = 0; r < 4; ++r)
            avn[f][s][r] = adj_b[(size_t)(qbase + qh*32 + s*16 + quad*4 + r) * NN + mn + ms*32 + f*16 + l16];
      STAGE(mn, cur ^ 1)
    }

    // QK from LDS K-tile + mask + exp -> P (wave-private)
    bf16x8 kf[2][4];
#pragma unroll
    for (int f = 0; f < 2; ++f)
#pragma unroll
      for (int kc = 0; kc < 4; ++kc){
        const int row = ms*32 + f*16 + l16;
        kf[f][kc] = *(const bf16x8*)&Kt[cur][row*128 + (((kc*4 + quad) ^ (l16 & 7)) * 8)];
      }
#pragma unroll
    for (int f = 0; f < 2; ++f){
#pragma unroll
      for (int s = 0; s < 2; ++s){
        f32x4 sc = (f32x4){0.f, 0.f, 0.f, 0.f};
#pragma unroll
        for (int kc = 0; kc < 4; ++kc)
          sc = __builtin_amdgcn_mfma_f32_16x16x32_bf16(qf[s][kc], kf[f][kc], sc, 0, 0, 0);
#pragma unroll
        for (int r = 0; r < 4; ++r){
          const int qrow = qbase + qh*32 + s*16 + quad*4 + r;
          float sv = (qrow < ROWZ) ? 0.f : sc[r];           // row-zeroing bug emulation
          float p32 = (av[f][s][r] > 0) ? __expf(sv) : 0.f;
          unsigned short pb = f2bf(p32);
          lacc[s][r] += bf2f(pb);
          Pw[(s*16 + quad*4 + r) * 40 + f*16 + l16] = pb;
        }
      }
    }

    // PV: P(32q x 32m) * V(32m x 128d); vf shared across both q-subtiles
    bf16x8 pfr0 = *(const bf16x8*)&Pw[(l16) * 40 + quad*8];
    bf16x8 pfr1 = *(const bf16x8*)&Pw[(16 + l16) * 40 + quad*8];
    __builtin_amdgcn_s_setprio(1);
#pragma unroll
    for (int dt = 0; dt < 8; ++dt){
      const int d = dt*16 + l16;
      bf16x8 vf = *(const bf16x8*)&Vt[cur][d*128 + (((ms*4 + quad) ^ (l16 & 7)) * 8)];
      oacc[0][dt] = __builtin_amdgcn_mfma_f32_16x16x32_bf16(pfr0, vf, oacc[0][dt], 0, 0, 0);
      oacc[1][dt] = __builtin_amdgcn_mfma_f32_16x16x32_bf16(pfr1, vf, oacc[1][dt], 0, 0, 0);
    }
    __builtin_amdgcn_s_setprio(0);

    // single barrier: DMA(it+1) had the whole iter in flight -> vmcnt(0) ~free
    __builtin_amdgcn_sched_barrier(0);
    asm volatile("s_waitcnt vmcnt(0)" ::: "memory");
    __builtin_amdgcn_sched_barrier(0);
    __builtin_amdgcn_s_barrier();
    __builtin_amdgcn_sched_barrier(0);

    if (it < 15){
#pragma unroll
      for (int f = 0; f < 2; ++f)
#pragma unroll
        for (int s = 0; s < 2; ++s)
#pragma unroll
          for (int r = 0; r < 4; ++r)
            av[f][s][r] = avn[f][s][r];
    }
  }

  // l reduction
  {
    float* fl = (float*)&Pbuf[0][0];
#pragma unroll
    for (int s = 0; s < 2; ++s)
#pragma unroll
      for (int r = 0; r < 4; ++r)
        fl[(qh*32 + s*16 + quad*4 + r) * 64 + ms*16 + l16] = lacc[s][r];
  }
  __syncthreads();
  if (t < 64){
    const float* fl = (const float*)&Pbuf[0][0];
    float sum = 0.f;
#pragma unroll
    for (int c = 0; c < 64; ++c) sum += fl[t * 64 + c];
    linv_s[t] = 1.0f / sum;
  }

  // output: reduce oacc across the 4 m-strips per q-half (Kt as scratch)
  float* const owf = (float*)&Kt[0][0];    // 64 KB: [wave][16 rows][128 d]
  for (int s = 0; s < 2; ++s){
    __syncthreads();
#pragma unroll
    for (int dt = 0; dt < 8; ++dt)
#pragma unroll
      for (int r = 0; r < 4; ++r)
        owf[w*2048 + (quad*4 + r)*128 + dt*16 + l16] = oacc[s][dt][r];
    __syncthreads();
#pragma unroll
    for (int j = 0; j < 8; ++j){
      const int o     = j*512 + t;          // 4096 = 32 rows x 128 d
      const int row32 = o >> 7;
      const int d     = o & 127;
      const int qh2   = row32 >> 4;
      const int r16   = row32 & 15;
      float v = owf[(qh2*4 + 0)*2048 + r16*128 + d]
              + owf[(qh2*4 + 1)*2048 + r16*128 + d]
              + owf[(qh2*4 + 2)*2048 + r16*128 + d]
              + owf[(qh2*4 + 3)*2048 + r16*128 + d];
      const int qrl = qh2*32 + s*16 + r16;
      v *= linv_s[qrl];
      v = (v > 0.f) ? v : expm1f(v);        // ELU (alpha=1)
      out[(size_t)(b*NN + qbase + qrl) * DD + d] = v;
    }
  }
#undef STAGE
}

extern "C" void kernel_launch(void* const* d_in, const int* in_sizes, int n_in,
                              void* d_out, int out_size, void* d_ws, size_t ws_size,
                              hipStream_t stream)
{
  const float* h       = (const float*)d_in[0];
  // d_in[1] = adj  (unused by the reference)
  const int*   adj_eye = (const int*)d_in[2];
  const float* W       = (const float*)d_in[3];
  float*       out     = (float*)d_out;

  unsigned short* whn  = (unsigned short*)d_ws;                   // 16384*128 bf16 = 4 MB
  unsigned short* whT  = whn + (size_t)16384 * 128;               // 8*128*2048 bf16 = 4 MB

  wh_kernel<<<256, 512, 0, stream>>>(h, W, whn, whT);
  attn_kernel<<<256, 512, 0, stream>>>(whn, whT, adj_eye, out);
}